// Round 10
// baseline (1001.941 us; speedup 1.0000x reference)
//
#include <hip/hip_runtime.h>

typedef __bf16 bf16_t;
typedef __bf16 bf16x8 __attribute__((ext_vector_type(8)));
typedef __bf16 bf16x4 __attribute__((ext_vector_type(4)));
typedef __bf16 bf16x2 __attribute__((ext_vector_type(2)));
typedef float f32x4 __attribute__((ext_vector_type(4)));

#define SCALE 0.17677669529663687f

__device__ __forceinline__ f32x4 mfma16(bf16x8 a, bf16x8 b, f32x4 c) {
  return __builtin_amdgcn_mfma_f32_16x16x32_bf16(a, b, c, 0, 0, 0);
}

// XOR-swizzled LDS byte offset: 16B-granule index XORed with (row&7).
__device__ __forceinline__ int swz(int row, int colByte, int strideB) {
  return row * strideB + ((((colByte >> 4) ^ (row & 7)) << 4) | (colByte & 15));
}

// lgkm-only barrier: orders LDS producer->consumer, leaves global loads in
// flight (no vmcnt drain). Proven r5-r7.
__device__ __forceinline__ void barrier_nd() {
  asm volatile("s_waitcnt lgkmcnt(0)" ::: "memory");
  __builtin_amdgcn_s_barrier();
  asm volatile("" ::: "memory");
}

union CvtU { bf16x2 h; unsigned int u; };
union PaU { unsigned int u[4]; bf16x8 v; };

// ws: bf16 weights. q_wb [0,36864) PRE-SCALED by SCALE, kv_wb [36864,110592),
// proj_wb [110592,147456). 294912 bytes.
__global__ void prep(const float* __restrict__ qw, const float* __restrict__ kvw,
                     const float* __restrict__ pw, bf16_t* __restrict__ wsb) {
  int i = blockIdx.x * 256 + threadIdx.x;
#pragma unroll
  for (int j = 0; j < 4; ++j) {
    int e = i * 4 + j;
    float v;
    if (e < 36864) v = qw[e] * SCALE;
    else if (e < 110592) v = kvw[e - 36864];
    else v = pw[e - 110592];
    wsb[e] = (bf16_t)v;
  }
}

template <bool WS>
__device__ __forceinline__ bf16x8 ldw(const bf16_t* __restrict__ wb,
                                      const float* __restrict__ wf, int off) {
  if constexpr (WS) {
    return *(const bf16x8*)(wb + off);
  } else {
    const float4* p = (const float4*)(wf + off);
    float4 a = p[0], c = p[1];
    bf16x8 r;
    r[0] = (bf16_t)a.x; r[1] = (bf16_t)a.y; r[2] = (bf16_t)a.z; r[3] = (bf16_t)a.w;
    r[4] = (bf16_t)c.x; r[5] = (bf16_t)c.y; r[6] = (bf16_t)c.z; r[7] = (bf16_t)c.w;
    return r;
  }
}

// One block = ONE window, 512 threads = 8 waves, LDS 72 KB -> TWO blocks/CU
// (phase-offset overlap: one block's memory bursts hide under the other's
// compute). r7's weight preloads + 4-barrier structure; x1 prefetched into
// VGPRs at stage time (phase A covers its HBM latency).
//   R0 @     0 : x2 staged -> Q -> att-out  (stride 384, swz)
//   R1 @ 24576 : K                          (stride 384, swz)
//   R2 @ 49152 : V^T [192][64]              (stride 128, swz)
template <bool WS>
__global__ __launch_bounds__(512, 2) void wca_main(
    const float* __restrict__ x1, const float* __restrict__ x2,
    const float* __restrict__ mask,
    const float* __restrict__ qw_f, const float* __restrict__ qb,
    const float* __restrict__ kvw_f, const float* __restrict__ kvb,
    const float* __restrict__ pw_f, const float* __restrict__ pb,
    const float* __restrict__ table,
    const bf16_t* __restrict__ wsb,
    float* __restrict__ out) {
  extern __shared__ char smem[];
  char* R0 = smem;
  char* R1 = smem + 24576;
  char* R2 = smem + 49152;

  const int t = threadIdx.x;
  const int w = t >> 6, l = t & 63, lo = l & 15, hi = l >> 4;
  const int b = blockIdx.x;
  const int rtB = w & 3, cgB = w >> 2;

  const bf16_t* q_wb = wsb;
  const bf16_t* kv_wb = wsb + 36864;
  const bf16_t* p_wb = wsb + 110592;

  // ---------- stage: issue x2 loads, then x1 prefetch, then convert ----------
  float4 xa[6], xb[6];  // x1 prefetch, consumed in phase B (2 barriers later)
  {
    const float4* s2 = (const float4*)(x2 + (size_t)b * 12288);
    float4 ld[6];
#pragma unroll
    for (int it = 0; it < 3; ++it) {
      int idx = it * 512 + t;
      ld[2 * it] = s2[2 * idx];
      ld[2 * it + 1] = s2[2 * idx + 1];
    }
    const float4* x1p = (const float4*)(x1 + (size_t)b * 12288 + (rtB * 16 + lo) * 192);
#pragma unroll
    for (int kk = 0; kk < 6; ++kk) {
      xa[kk] = x1p[kk * 8 + hi * 2];
      xb[kk] = x1p[kk * 8 + hi * 2 + 1];
    }
#pragma unroll
    for (int it = 0; it < 3; ++it) {
      int idx = it * 512 + t;
      int n = idx / 24, g = idx - n * 24;
      float4 a = ld[2 * it], c = ld[2 * it + 1];
      bf16x8 v;
      v[0] = (bf16_t)a.x; v[1] = (bf16_t)a.y; v[2] = (bf16_t)a.z; v[3] = (bf16_t)a.w;
      v[4] = (bf16_t)c.x; v[5] = (bf16_t)c.y; v[6] = (bf16_t)c.z; v[7] = (bf16_t)c.w;
      *(bf16x8*)(R0 + swz(n, g * 16, 384)) = v;
    }
  }
  barrier_nd();

  // ---------- phase A: KV proj, 18 weight frags preloaded ----------
  // wave w: K cols w*48.. (w<4) | V cols (w-4)*48.. (w>=4)
  {
    const int part = w >> 2;            // 0 = K, 1 = V
    const int kcol = (w & 3) * 48;
    bf16x8 wA[6][3];
#pragma unroll
    for (int kk = 0; kk < 6; ++kk)
#pragma unroll
      for (int ct = 0; ct < 3; ++ct) {
        int row = part * 192 + kcol + ct * 16 + lo;
        wA[kk][ct] = ldw<WS>(kv_wb, kvw_f, row * 192 + kk * 32 + hi * 8);
      }
    f32x4 acc[4][3];
#pragma unroll
    for (int rt = 0; rt < 4; ++rt)
#pragma unroll
      for (int ct = 0; ct < 3; ++ct) { f32x4 z = {0.f, 0.f, 0.f, 0.f}; acc[rt][ct] = z; }
#pragma unroll
    for (int kk = 0; kk < 6; ++kk) {
      bf16x8 a[4];
#pragma unroll
      for (int rt = 0; rt < 4; ++rt)
        a[rt] = *(const bf16x8*)(R0 + swz(rt * 16 + lo, (kk * 4 + hi) * 16, 384));
#pragma unroll
      for (int rt = 0; rt < 4; ++rt)
#pragma unroll
        for (int ct = 0; ct < 3; ++ct)
          acc[rt][ct] = mfma16(a[rt], wA[kk][ct], acc[rt][ct]);
    }
    if (part == 0) {
#pragma unroll
      for (int ct = 0; ct < 3; ++ct) {
        int och = kcol + ct * 16 + lo;
        float bv = kvb[och];
#pragma unroll
        for (int rt = 0; rt < 4; ++rt)
#pragma unroll
          for (int i = 0; i < 4; ++i)
            *(bf16_t*)(R1 + swz(rt * 16 + hi * 4 + i, och * 2, 384)) =
                (bf16_t)(acc[rt][ct][i] + bv);
      }
    } else {
#pragma unroll
      for (int ct = 0; ct < 3; ++ct) {
        int och = kcol + ct * 16 + lo;
        float bv = kvb[192 + och];
#pragma unroll
        for (int rt = 0; rt < 4; ++rt) {
          int n0 = rt * 16 + hi * 4;
          bf16x4 pk;
#pragma unroll
          for (int i = 0; i < 4; ++i) pk[i] = (bf16_t)(acc[rt][ct][i] + bv);
          *(bf16x4*)(R2 + swz(och, n0 * 2, 128)) = pk;
        }
      }
    }
  }
  barrier_nd();  // x2 reads done; K, V^T ready

  // ---------- phase B: Q proj from prefetched x1 -> R0 ----------
  // wave: rtB = w&3 (16 rows), cgB = w>>2 (96 cols)
  {
    f32x4 acc[6];
#pragma unroll
    for (int ct = 0; ct < 6; ++ct) { f32x4 z = {0.f, 0.f, 0.f, 0.f}; acc[ct] = z; }
#pragma unroll
    for (int kh = 0; kh < 2; ++kh) {
      bf16x8 wB[3][6];
#pragma unroll
      for (int k2 = 0; k2 < 3; ++k2)
#pragma unroll
        for (int ct = 0; ct < 6; ++ct) {
          int col = cgB * 96 + ct * 16 + lo;
          wB[k2][ct] = ldw<WS>(q_wb, qw_f, col * 192 + (kh * 3 + k2) * 32 + hi * 8);
        }
#pragma unroll
      for (int k2 = 0; k2 < 3; ++k2) {
        int kk = kh * 3 + k2;
        bf16x8 a;
        a[0] = (bf16_t)xa[kk].x; a[1] = (bf16_t)xa[kk].y;
        a[2] = (bf16_t)xa[kk].z; a[3] = (bf16_t)xa[kk].w;
        a[4] = (bf16_t)xb[kk].x; a[5] = (bf16_t)xb[kk].y;
        a[6] = (bf16_t)xb[kk].z; a[7] = (bf16_t)xb[kk].w;
#pragma unroll
        for (int ct = 0; ct < 6; ++ct) acc[ct] = mfma16(a, wB[k2][ct], acc[ct]);
      }
    }
#pragma unroll
    for (int ct = 0; ct < 6; ++ct) {
      int col = cgB * 96 + ct * 16 + lo;
#pragma unroll
      for (int i = 0; i < 4; ++i) {
        float val = WS ? (acc[ct][i] + qb[col] * SCALE)
                       : (acc[ct][i] + qb[col]) * SCALE;
        *(bf16_t*)(R0 + swz(rtB * 16 + hi * 4 + i, col * 2, 384)) = (bf16_t)val;
      }
    }
  }
  barrier_nd();  // Q ready

  // ---------- attention: wave = (rt3 = w>>1, hh = w&1) ----------
  // 16 rows x 3 heads; att-out overwrites this wave's own Q tile in R0
  // (rows x head-half cols disjoint across waves; per-head read-before-write
  // within the wave) -> no per-head barriers.
  {
    const int rt3 = w >> 1, hh = w & 1, rbase = rt3 * 16;
    const int r = rbase + lo;
    const float* maskp = mask + (size_t)(b & 1023) * 4096 + r * 64;
    f32x4 mk[4];
    int ridx[4][4];
#pragma unroll
    for (int ct = 0; ct < 4; ++ct) {
      mk[ct] = *(const f32x4*)(maskp + ct * 16 + hi * 4);
#pragma unroll
      for (int i = 0; i < 4; ++i) {
        int c = ct * 16 + hi * 4 + i;
        ridx[ct][i] = (((r >> 3) - (c >> 3) + 7) * 15 + ((r & 7) - (c & 7) + 7)) * 6;
      }
    }
#pragma unroll
    for (int hq = 0; hq < 3; ++hq) {
      const int h = hh * 3 + hq;
      f32x4 cb[4];
#pragma unroll
      for (int ct = 0; ct < 4; ++ct) {
#pragma unroll
        for (int i = 0; i < 4; ++i) cb[ct][i] = table[ridx[ct][i] + h];
        cb[ct] += mk[ct];
      }
      bf16x8 qa = *(const bf16x8*)(R0 + swz(r, h * 64 + hi * 16, 384));
      f32x4 s[4];
#pragma unroll
      for (int ct = 0; ct < 4; ++ct) {
        bf16x8 ka = *(const bf16x8*)(R1 + swz(ct * 16 + lo, h * 64 + hi * 16, 384));
        s[ct] = mfma16(ka, qa, cb[ct]);  // lane holds S[r][ct*16+hi*4+i]
      }
      float mx = -1e30f;
#pragma unroll
      for (int ct = 0; ct < 4; ++ct)
#pragma unroll
        for (int i = 0; i < 4; ++i) mx = fmaxf(mx, s[ct][i]);
      mx = fmaxf(mx, __shfl_xor(mx, 16));
      mx = fmaxf(mx, __shfl_xor(mx, 32));
      float sum = 0.f;
#pragma unroll
      for (int ct = 0; ct < 4; ++ct)
#pragma unroll
        for (int i = 0; i < 4; ++i) {
          float p = __expf(s[ct][i] - mx);
          s[ct][i] = p;
          sum += p;
        }
      sum += __shfl_xor(sum, 16);
      sum += __shfl_xor(sum, 32);
      float rinv = 1.0f / sum;
      unsigned int word[4][2];
#pragma unroll
      for (int ct = 0; ct < 4; ++ct)
#pragma unroll
        for (int i2 = 0; i2 < 2; ++i2) {
          CvtU cu;
          cu.h[0] = (bf16_t)(s[ct][2 * i2] * rinv);
          cu.h[1] = (bf16_t)(s[ct][2 * i2 + 1] * rinv);
          word[ct][i2] = cu.u;
        }
      // PV: build A-frag P[rbase+lo][k-run] via shfl word-pulls
      f32x4 o0 = {0.f, 0.f, 0.f, 0.f}, o1 = {0.f, 0.f, 0.f, 0.f};
#pragma unroll
      for (int k2 = 0; k2 < 2; ++k2) {
        PaU pa;
#pragma unroll
        for (int j2 = 0; j2 < 4; ++j2) {
          int src = lo + ((hi & 1) << 5) + ((j2 >> 1) << 4);
          unsigned int wa = (unsigned int)__shfl((int)word[2 * k2][j2 & 1], src);
          unsigned int wb = (unsigned int)__shfl((int)word[2 * k2 + 1][j2 & 1], src);
          pa.u[j2] = (hi & 2) ? wb : wa;
        }
        bf16x8 v0 = *(const bf16x8*)(R2 + swz(h * 32 + lo, k2 * 64 + hi * 16, 128));
        bf16x8 v1 = *(const bf16x8*)(R2 + swz(h * 32 + 16 + lo, k2 * 64 + hi * 16, 128));
        o0 = mfma16(pa.v, v0, o0);
        o1 = mfma16(pa.v, v1, o1);
      }
#pragma unroll
      for (int i = 0; i < 4; ++i) {
        int rr = rbase + hi * 4 + i;
        *(bf16_t*)(R0 + swz(rr, h * 64 + lo * 2, 384)) = (bf16_t)o0[i];
        *(bf16_t*)(R0 + swz(rr, h * 64 + 32 + lo * 2, 384)) = (bf16_t)o1[i];
      }
    }
  }
  barrier_nd();  // att-out fully in R0

  // ---------- out proj: wave = (rtB, cgB), weights batched per kh ----------
  {
    f32x4 acc[6];
#pragma unroll
    for (int ct = 0; ct < 6; ++ct) { f32x4 z = {0.f, 0.f, 0.f, 0.f}; acc[ct] = z; }
#pragma unroll
    for (int kh = 0; kh < 2; ++kh) {
      bf16x8 wB[3][6];
#pragma unroll
      for (int k2 = 0; k2 < 3; ++k2)
#pragma unroll
        for (int ct = 0; ct < 6; ++ct) {
          int col = cgB * 96 + ct * 16 + lo;
          wB[k2][ct] = ldw<WS>(p_wb, pw_f, col * 192 + (kh * 3 + k2) * 32 + hi * 8);
        }
#pragma unroll
      for (int k2 = 0; k2 < 3; ++k2) {
        bf16x8 a = *(const bf16x8*)(
            R0 + swz(rtB * 16 + lo, ((kh * 3 + k2) * 4 + hi) * 16, 384));
#pragma unroll
        for (int ct = 0; ct < 6; ++ct) acc[ct] = mfma16(a, wB[k2][ct], acc[ct]);
      }
    }
    float* outp = out + (size_t)b * 12288;
#pragma unroll
    for (int ct = 0; ct < 6; ++ct) {
      int col = cgB * 96 + ct * 16 + lo;
      float bv = pb[col];
#pragma unroll
      for (int i = 0; i < 4; ++i)
        outp[(rtB * 16 + hi * 4 + i) * 192 + col] = acc[ct][i] + bv;
    }
  }
}

extern "C" void kernel_launch(void* const* d_in, const int* in_sizes, int n_in,
                              void* d_out, int out_size, void* d_ws, size_t ws_size,
                              hipStream_t stream) {
  const float* x1 = (const float*)d_in[0];
  const float* x2 = (const float*)d_in[1];
  const float* mask = (const float*)d_in[2];
  const float* qw = (const float*)d_in[3];
  const float* qb = (const float*)d_in[4];
  const float* kvw = (const float*)d_in[5];
  const float* kvb = (const float*)d_in[6];
  const float* pw = (const float*)d_in[7];
  const float* pb = (const float*)d_in[8];
  const float* table = (const float*)d_in[9];
  float* out = (float*)d_out;
  bf16_t* wsb = (bf16_t*)d_ws;
  const int LDS_BYTES = 73728;
  if (ws_size >= 294912) {
    prep<<<144, 256, 0, stream>>>(qw, kvw, pw, wsb);
    wca_main<true><<<8192, 512, LDS_BYTES, stream>>>(x1, x2, mask, qw, qb, kvw, kvb,
                                                     pw, pb, table, wsb, out);
  } else {
    wca_main<false><<<8192, 512, LDS_BYTES, stream>>>(x1, x2, mask, qw, qb, kvw, kvb,
                                                      pw, pb, table, wsb, out);
  }
}

// Round 11
// 720.654 us; speedup vs baseline: 1.3903x; 1.3903x over previous
//
#include <hip/hip_runtime.h>

typedef __bf16 bf16_t;
typedef __bf16 bf16x8 __attribute__((ext_vector_type(8)));
typedef __bf16 bf16x4 __attribute__((ext_vector_type(4)));
typedef __bf16 bf16x2 __attribute__((ext_vector_type(2)));
typedef float f32x4 __attribute__((ext_vector_type(4)));

#define SCALE 0.17677669529663687f

// Verified mapping: mfma16(A,B) -> lane(lo,hi)[i] = D[B-row=lo][A-row=hi*4+i]
//                                = sum_k A[hi*4+i,k] * B[lo,k]
__device__ __forceinline__ f32x4 mfma16(bf16x8 a, bf16x8 b, f32x4 c) {
  return __builtin_amdgcn_mfma_f32_16x16x32_bf16(a, b, c, 0, 0, 0);
}

// XOR-swizzled LDS byte offset: 16B-granule index XORed with (row&7).
__device__ __forceinline__ int swz(int row, int colByte, int strideB) {
  return row * strideB + ((((colByte >> 4) ^ (row & 7)) << 4) | (colByte & 15));
}

// lgkm-only barrier: orders LDS producer->consumer, leaves global loads in
// flight. Proven r5-r10.
__device__ __forceinline__ void barrier_nd() {
  asm volatile("s_waitcnt lgkmcnt(0)" ::: "memory");
  __builtin_amdgcn_s_barrier();
  asm volatile("" ::: "memory");
}

union CvtU { bf16x2 h; unsigned int u; };
union PaU { unsigned int u[4]; bf16x8 v; };

// ws: bf16 weights. q_wb [0,36864) PRE-SCALED by SCALE, kv_wb [36864,110592),
// proj_wb [110592,147456). 294912 bytes.
__global__ void prep(const float* __restrict__ qw, const float* __restrict__ kvw,
                     const float* __restrict__ pw, bf16_t* __restrict__ wsb) {
  int i = blockIdx.x * 256 + threadIdx.x;
#pragma unroll
  for (int j = 0; j < 4; ++j) {
    int e = i * 4 + j;
    float v;
    if (e < 36864) v = qw[e] * SCALE;
    else if (e < 110592) v = kvw[e - 36864];
    else v = pw[e - 110592];
    wsb[e] = (bf16_t)v;
  }
}

template <bool WS>
__device__ __forceinline__ bf16x8 ldw(const bf16_t* __restrict__ wb,
                                      const float* __restrict__ wf, int off) {
  if constexpr (WS) {
    return *(const bf16x8*)(wb + off);
  } else {
    const float4* p = (const float4*)(wf + off);
    float4 a = p[0], c = p[1];
    bf16x8 r;
    r[0] = (bf16_t)a.x; r[1] = (bf16_t)a.y; r[2] = (bf16_t)a.z; r[3] = (bf16_t)a.w;
    r[4] = (bf16_t)c.x; r[5] = (bf16_t)c.y; r[6] = (bf16_t)c.z; r[7] = (bf16_t)c.w;
    return r;
  }
}

// One block = TWO windows (win0=2b, win1=2b+1). 512 threads = 8 waves.
// LDS = 144 KB (1 block/CU -- occupancy is register-pinned anyway, see r10):
//   RA @      0 : [128][384B] x2 staged -> Q -> att-out (rows wv*64+n, swz)
//   RK @  49152 : [128][384B] K (swz)
//   RV @  98304 : [2][192][128B] V^T per window (swz)
// r11 changes vs r7: operand-swapped K/Q/PV MFMAs so LDS writes pack to b64;
// B->attn barrier removed (same-wave Q tile); x1 kh0 prefetched across the
// A->B barrier; mask loads hidden under phase-B MFMAs.
template <bool WS>
__global__ __launch_bounds__(512, 2) void wca_main(
    const float* __restrict__ x1, const float* __restrict__ x2,
    const float* __restrict__ mask,
    const float* __restrict__ qw_f, const float* __restrict__ qb,
    const float* __restrict__ kvw_f, const float* __restrict__ kvb,
    const float* __restrict__ pw_f, const float* __restrict__ pb,
    const float* __restrict__ table,
    const bf16_t* __restrict__ wsb,
    float* __restrict__ out) {
  extern __shared__ char smem[];
  char* RA = smem;
  char* RK = smem + 49152;
  char* RV = smem + 98304;

  const int t = threadIdx.x;
  const int w = t >> 6, l = t & 63, lo = l & 15, hi = l >> 4;
  const int win0 = 2 * blockIdx.x;
  // phase-B / attention wave mapping (identical so B->T needs no barrier):
  const int wvB = w >> 2, rt2 = (w >> 1) & 1, hh = w & 1;

  const bf16_t* q_wb = wsb;
  const bf16_t* kv_wb = wsb + 36864;
  const bf16_t* p_wb = wsb + 110592;

  // ---------- stage x2 (both windows) -> RA ----------
  {
    const float4* s2a = (const float4*)(x2 + (size_t)win0 * 12288);
    const float4* s2b = (const float4*)(x2 + (size_t)(win0 + 1) * 12288);
    float4 ld[12];
#pragma unroll
    for (int it = 0; it < 3; ++it) {
      int idx = it * 512 + t;
      ld[4 * it + 0] = s2a[2 * idx]; ld[4 * it + 1] = s2a[2 * idx + 1];
      ld[4 * it + 2] = s2b[2 * idx]; ld[4 * it + 3] = s2b[2 * idx + 1];
    }
#pragma unroll
    for (int it = 0; it < 3; ++it) {
      int idx = it * 512 + t;
      int n = idx / 24, g = idx - n * 24;
      bf16x8 v;
      float4 a = ld[4 * it + 0], c = ld[4 * it + 1];
      v[0] = (bf16_t)a.x; v[1] = (bf16_t)a.y; v[2] = (bf16_t)a.z; v[3] = (bf16_t)a.w;
      v[4] = (bf16_t)c.x; v[5] = (bf16_t)c.y; v[6] = (bf16_t)c.z; v[7] = (bf16_t)c.w;
      *(bf16x8*)(RA + swz(n, g * 16, 384)) = v;
      a = ld[4 * it + 2]; c = ld[4 * it + 3];
      v[0] = (bf16_t)a.x; v[1] = (bf16_t)a.y; v[2] = (bf16_t)a.z; v[3] = (bf16_t)a.w;
      v[4] = (bf16_t)c.x; v[5] = (bf16_t)c.y; v[6] = (bf16_t)c.z; v[7] = (bf16_t)c.w;
      *(bf16x8*)(RA + swz(64 + n, g * 16, 384)) = v;
    }
  }
  barrier_nd();

  // ---------- phase A: KV proj (+ x1 kh0 prefetch for phase B) ----------
  // wave w: K cols (w&3)*48 (w<4) | V cols (w&3)*48 (w>=4), both windows.
  float4 xp[12];  // x1 kh0 half, crosses A->B barrier (48 VGPR, r10-proven)
  {
    const int part = w >> 2;            // 0 = K, 1 = V
    const int kcol = (w & 3) * 48;
    bf16x8 wA[6][3];
#pragma unroll
    for (int kk = 0; kk < 6; ++kk)
#pragma unroll
      for (int ct = 0; ct < 3; ++ct) {
        int row = part * 192 + kcol + ct * 16 + lo;
        wA[kk][ct] = ldw<WS>(kv_wb, kvw_f, row * 192 + kk * 32 + hi * 8);
      }
    {
      const float* x1w = x1 + (size_t)(win0 + wvB) * 12288;
#pragma unroll
      for (int rt = 0; rt < 2; ++rt) {
        const float4* p = (const float4*)(x1w + (rt2 * 32 + rt * 16 + lo) * 192);
#pragma unroll
        for (int k2 = 0; k2 < 3; ++k2) {
          xp[rt * 6 + k2 * 2 + 0] = p[k2 * 8 + hi * 2];
          xp[rt * 6 + k2 * 2 + 1] = p[k2 * 8 + hi * 2 + 1];
        }
      }
    }
    for (int wv = 0; wv < 2; ++wv) {
      f32x4 acc[4][3];
#pragma unroll
      for (int rt = 0; rt < 4; ++rt)
#pragma unroll
        for (int ct = 0; ct < 3; ++ct) { f32x4 z = {0.f, 0.f, 0.f, 0.f}; acc[rt][ct] = z; }
#pragma unroll
      for (int kk = 0; kk < 6; ++kk) {
        bf16x8 a[4];
#pragma unroll
        for (int rt = 0; rt < 4; ++rt)
          a[rt] = *(const bf16x8*)(RA + swz(wv * 64 + rt * 16 + lo, (kk * 4 + hi) * 16, 384));
        if (part == 0) {
          // K swapped: lane holds K[n=rt*16+lo][och=kcol+ct*16+hi*4+i]
#pragma unroll
          for (int rt = 0; rt < 4; ++rt)
#pragma unroll
            for (int ct = 0; ct < 3; ++ct)
              acc[rt][ct] = mfma16(wA[kk][ct], a[rt], acc[rt][ct]);
        } else {
          // V unswapped: lane holds V[n=rt*16+hi*4+i][och=kcol+ct*16+lo]
#pragma unroll
          for (int rt = 0; rt < 4; ++rt)
#pragma unroll
            for (int ct = 0; ct < 3; ++ct)
              acc[rt][ct] = mfma16(a[rt], wA[kk][ct], acc[rt][ct]);
        }
      }
      if (part == 0) {
#pragma unroll
        for (int ct = 0; ct < 3; ++ct) {
          f32x4 bv4 = *(const f32x4*)(kvb + kcol + ct * 16 + hi * 4);
#pragma unroll
          for (int rt = 0; rt < 4; ++rt) {
            bf16x4 pk;
#pragma unroll
            for (int i = 0; i < 4; ++i) pk[i] = (bf16_t)(acc[rt][ct][i] + bv4[i]);
            *(bf16x4*)(RK + swz(wv * 64 + rt * 16 + lo,
                                kcol * 2 + ct * 32 + hi * 8, 384)) = pk;
          }
        }
      } else {
#pragma unroll
        for (int ct = 0; ct < 3; ++ct) {
          int och = kcol + ct * 16 + lo;
          float bv = kvb[192 + och];
#pragma unroll
          for (int rt = 0; rt < 4; ++rt) {
            int n0 = rt * 16 + hi * 4;
            bf16x4 pk;
#pragma unroll
            for (int i = 0; i < 4; ++i) pk[i] = (bf16_t)(acc[rt][ct][i] + bv);
            *(bf16x4*)(RV + wv * 24576 + swz(och, n0 * 2, 128)) = pk;
          }
        }
      }
    }
  }
  barrier_nd();  // x2 reads done; K, V^T ready

  // ---------- phase B: Q proj (swapped, packed writes) + mask prefetch ----------
  // wave (wvB, rt2, hh): rows rt2*32..+32, cols hh*96..+96 of window wvB.
  f32x4 mk[2][4];  // mask rows, consumed by attention (no barrier between)
  {
    const float* x1w = x1 + (size_t)(win0 + wvB) * 12288;
    // issue kh=1 x1 loads immediately (arrive under kh0 MFMAs)
    float4 xq[12];
#pragma unroll
    for (int rt = 0; rt < 2; ++rt) {
      const float4* p = (const float4*)(x1w + (rt2 * 32 + rt * 16 + lo) * 192);
#pragma unroll
      for (int k2 = 0; k2 < 3; ++k2) {
        xq[rt * 6 + k2 * 2 + 0] = p[(3 + k2) * 8 + hi * 2];
        xq[rt * 6 + k2 * 2 + 1] = p[(3 + k2) * 8 + hi * 2 + 1];
      }
    }
    f32x4 acc[2][6];
#pragma unroll
    for (int rt = 0; rt < 2; ++rt)
#pragma unroll
      for (int ct = 0; ct < 6; ++ct) { f32x4 z = {0.f, 0.f, 0.f, 0.f}; acc[rt][ct] = z; }
    // kh0 from xp (prefetched across the barrier)
    {
      bf16x8 wB[3][6];
#pragma unroll
      for (int k2 = 0; k2 < 3; ++k2)
#pragma unroll
        for (int ct = 0; ct < 6; ++ct) {
          int col = hh * 96 + ct * 16 + lo;
          wB[k2][ct] = ldw<WS>(q_wb, qw_f, col * 192 + k2 * 32 + hi * 8);
        }
#pragma unroll
      for (int k2 = 0; k2 < 3; ++k2)
#pragma unroll
        for (int rt = 0; rt < 2; ++rt) {
          float4 xa = xp[rt * 6 + k2 * 2], xb = xp[rt * 6 + k2 * 2 + 1];
          bf16x8 a;
          a[0] = (bf16_t)xa.x; a[1] = (bf16_t)xa.y; a[2] = (bf16_t)xa.z; a[3] = (bf16_t)xa.w;
          a[4] = (bf16_t)xb.x; a[5] = (bf16_t)xb.y; a[6] = (bf16_t)xb.z; a[7] = (bf16_t)xb.w;
#pragma unroll
          for (int ct = 0; ct < 6; ++ct)
            acc[rt][ct] = mfma16(wB[k2][ct], a, acc[rt][ct]);
        }
    }
    // mask prefetch (xp now dead; latency hides under kh1)
    {
      const float* maskb = mask + (size_t)((win0 + wvB) & 1023) * 4096;
#pragma unroll
      for (int rts = 0; rts < 2; ++rts) {
        int r = rt2 * 32 + rts * 16 + lo;
#pragma unroll
        for (int ct = 0; ct < 4; ++ct)
          mk[rts][ct] = *(const f32x4*)(maskb + r * 64 + ct * 16 + hi * 4);
      }
    }
    // kh1 from xq
    {
      bf16x8 wB[3][6];
#pragma unroll
      for (int k2 = 0; k2 < 3; ++k2)
#pragma unroll
        for (int ct = 0; ct < 6; ++ct) {
          int col = hh * 96 + ct * 16 + lo;
          wB[k2][ct] = ldw<WS>(q_wb, qw_f, col * 192 + (3 + k2) * 32 + hi * 8);
        }
#pragma unroll
      for (int k2 = 0; k2 < 3; ++k2)
#pragma unroll
        for (int rt = 0; rt < 2; ++rt) {
          float4 xa = xq[rt * 6 + k2 * 2], xb = xq[rt * 6 + k2 * 2 + 1];
          bf16x8 a;
          a[0] = (bf16_t)xa.x; a[1] = (bf16_t)xa.y; a[2] = (bf16_t)xa.z; a[3] = (bf16_t)xa.w;
          a[4] = (bf16_t)xb.x; a[5] = (bf16_t)xb.y; a[6] = (bf16_t)xb.z; a[7] = (bf16_t)xb.w;
#pragma unroll
          for (int ct = 0; ct < 6; ++ct)
            acc[rt][ct] = mfma16(wB[k2][ct], a, acc[rt][ct]);
        }
    }
    // write Q packed: lane holds Q[n=rt2*32+rt*16+lo][col=hh*96+ct*16+hi*4+i]
#pragma unroll
    for (int ct = 0; ct < 6; ++ct) {
      f32x4 qb4 = *(const f32x4*)(qb + hh * 96 + ct * 16 + hi * 4);
#pragma unroll
      for (int rt = 0; rt < 2; ++rt) {
        int row = wvB * 64 + rt2 * 32 + rt * 16 + lo;
        bf16x4 pk;
#pragma unroll
        for (int i = 0; i < 4; ++i) {
          float val = WS ? (acc[rt][ct][i] + qb4[i] * SCALE)
                         : (acc[rt][ct][i] + qb4[i]) * SCALE;
          pk[i] = (bf16_t)val;
        }
        *(bf16x4*)(RA + swz(row, hh * 192 + ct * 32 + hi * 8, 384)) = pk;
      }
    }
  }
  // NO barrier: attention wave == phase-B wave for its Q tile; K/V synced at
  // the A-barrier; same-wave LDS ops are in-order.

  // ---------- attention: wave = (wvB, rt2, hh), 32 rows x 3 heads ----------
  {
#pragma unroll
    for (int hq = 0; hq < 3; ++hq) {
      const int h = hh * 3 + hq;
#pragma unroll
      for (int rts = 0; rts < 2; ++rts) {
        const int rbase = rt2 * 32 + rts * 16;
        const int r = rbase + lo;
        bf16x8 qa = *(const bf16x8*)(RA + swz(wvB * 64 + r, h * 64 + hi * 16, 384));
        f32x4 s[4];
#pragma unroll
        for (int ct = 0; ct < 4; ++ct) {
          f32x4 ci;
#pragma unroll
          for (int i = 0; i < 4; ++i) {
            int c = ct * 16 + hi * 4 + i;
            int rel = (((r >> 3) - (c >> 3) + 7) * 15 + ((r & 7) - (c & 7) + 7)) * 6;
            ci[i] = table[rel + h];
          }
          ci += mk[rts][ct];
          bf16x8 ka = *(const bf16x8*)(RK + swz(wvB * 64 + ct * 16 + lo, h * 64 + hi * 16, 384));
          s[ct] = mfma16(ka, qa, ci);  // lane holds S[r][ct*16+hi*4+i]
        }
        float mx = -1e30f;
#pragma unroll
        for (int ct = 0; ct < 4; ++ct)
#pragma unroll
          for (int i = 0; i < 4; ++i) mx = fmaxf(mx, s[ct][i]);
        mx = fmaxf(mx, __shfl_xor(mx, 16));
        mx = fmaxf(mx, __shfl_xor(mx, 32));
        float sum = 0.f;
#pragma unroll
        for (int ct = 0; ct < 4; ++ct)
#pragma unroll
          for (int i = 0; i < 4; ++i) {
            float p = __expf(s[ct][i] - mx);
            s[ct][i] = p;
            sum += p;
          }
        sum += __shfl_xor(sum, 16);
        sum += __shfl_xor(sum, 32);
        float rinv = 1.0f / sum;
        unsigned int word[4][2];
#pragma unroll
        for (int ct = 0; ct < 4; ++ct)
#pragma unroll
          for (int i2 = 0; i2 < 2; ++i2) {
            CvtU cu;
            cu.h[0] = (bf16_t)(s[ct][2 * i2] * rinv);
            cu.h[1] = (bf16_t)(s[ct][2 * i2 + 1] * rinv);
            word[ct][i2] = cu.u;
          }
        // PV (swapped): o = mfma16(v, pa) -> lane holds O[q=rbase+lo][ch=...hi*4+i]
        f32x4 o0 = {0.f, 0.f, 0.f, 0.f}, o1 = {0.f, 0.f, 0.f, 0.f};
#pragma unroll
        for (int k2 = 0; k2 < 2; ++k2) {
          PaU pa;
#pragma unroll
          for (int j2 = 0; j2 < 4; ++j2) {
            int src = lo + ((hi & 1) << 5) + ((j2 >> 1) << 4);
            unsigned int wa = (unsigned int)__shfl((int)word[2 * k2][j2 & 1], src);
            unsigned int wb = (unsigned int)__shfl((int)word[2 * k2 + 1][j2 & 1], src);
            pa.u[j2] = (hi & 2) ? wb : wa;
          }
          bf16x8 v0 = *(const bf16x8*)(RV + wvB * 24576 + swz(h * 32 + lo, k2 * 64 + hi * 16, 128));
          bf16x8 v1 = *(const bf16x8*)(RV + wvB * 24576 + swz(h * 32 + 16 + lo, k2 * 64 + hi * 16, 128));
          o0 = mfma16(v0, pa.v, o0);
          o1 = mfma16(v1, pa.v, o1);
        }
        // packed att-out: row = own q-row, ch packed in-lane
        bf16x4 p0, p1;
#pragma unroll
        for (int i = 0; i < 4; ++i) { p0[i] = (bf16_t)o0[i]; p1[i] = (bf16_t)o1[i]; }
        *(bf16x4*)(RA + swz(wvB * 64 + r, h * 64 + hi * 8, 384)) = p0;
        *(bf16x4*)(RA + swz(wvB * 64 + r, h * 64 + 32 + hi * 8, 384)) = p1;
      }
    }
  }
  barrier_nd();  // att-out fully in RA

  // ---------- out proj: wave = (wv = w>>2, cgo = w&3 -> 48 cols) ----------
  {
    const int wv = w >> 2, cgo = w & 3;
    bf16x8 wO[6][3];
#pragma unroll
    for (int kk = 0; kk < 6; ++kk)
#pragma unroll
      for (int ct = 0; ct < 3; ++ct) {
        int col = cgo * 48 + ct * 16 + lo;
        wO[kk][ct] = ldw<WS>(p_wb, pw_f, col * 192 + kk * 32 + hi * 8);
      }
    f32x4 acc[4][3];
#pragma unroll
    for (int rt = 0; rt < 4; ++rt)
#pragma unroll
      for (int ct = 0; ct < 3; ++ct) { f32x4 z = {0.f, 0.f, 0.f, 0.f}; acc[rt][ct] = z; }
#pragma unroll
    for (int kk = 0; kk < 6; ++kk) {
      bf16x8 a[4];
#pragma unroll
      for (int rt = 0; rt < 4; ++rt)
        a[rt] = *(const bf16x8*)(RA + swz(wv * 64 + rt * 16 + lo, (kk * 4 + hi) * 16, 384));
#pragma unroll
      for (int rt = 0; rt < 4; ++rt)
#pragma unroll
        for (int ct = 0; ct < 3; ++ct)
          acc[rt][ct] = mfma16(a[rt], wO[kk][ct], acc[rt][ct]);
    }
    float* outp = out + (size_t)(win0 + wv) * 12288;
#pragma unroll
    for (int ct = 0; ct < 3; ++ct) {
      int col = cgo * 48 + ct * 16 + lo;
      float bv = pb[col];
#pragma unroll
      for (int rt = 0; rt < 4; ++rt)
#pragma unroll
        for (int i = 0; i < 4; ++i)
          outp[(rt * 16 + hi * 4 + i) * 192 + col] = acc[rt][ct][i] + bv;
    }
  }
}

extern "C" void kernel_launch(void* const* d_in, const int* in_sizes, int n_in,
                              void* d_out, int out_size, void* d_ws, size_t ws_size,
                              hipStream_t stream) {
  const float* x1 = (const float*)d_in[0];
  const float* x2 = (const float*)d_in[1];
  const float* mask = (const float*)d_in[2];
  const float* qw = (const float*)d_in[3];
  const float* qb = (const float*)d_in[4];
  const float* kvw = (const float*)d_in[5];
  const float* kvb = (const float*)d_in[6];
  const float* pw = (const float*)d_in[7];
  const float* pb = (const float*)d_in[8];
  const float* table = (const float*)d_in[9];
  float* out = (float*)d_out;
  bf16_t* wsb = (bf16_t*)d_ws;
  const int LDS_BYTES = 147456;
  if (ws_size >= 294912) {
    prep<<<144, 256, 0, stream>>>(qw, kvw, pw, wsb);
    wca_main<true><<<4096, 512, LDS_BYTES, stream>>>(x1, x2, mask, qw, qb, kvw, kvb,
                                                     pw, pb, table, wsb, out);
  } else {
    wca_main<false><<<4096, 512, LDS_BYTES, stream>>>(x1, x2, mask, qw, qb, kvw, kvb,
                                                      pw, pb, table, wsb, out);
  }
}

// Round 12
// 652.472 us; speedup vs baseline: 1.5356x; 1.1045x over previous
//
#include <hip/hip_runtime.h>

typedef __bf16 bf16_t;
typedef __bf16 bf16x8 __attribute__((ext_vector_type(8)));
typedef __bf16 bf16x4 __attribute__((ext_vector_type(4)));
typedef __bf16 bf16x2 __attribute__((ext_vector_type(2)));
typedef float f32x4 __attribute__((ext_vector_type(4)));

#define SCALE 0.17677669529663687f

__device__ __forceinline__ f32x4 mfma16(bf16x8 a, bf16x8 b, f32x4 c) {
  return __builtin_amdgcn_mfma_f32_16x16x32_bf16(a, b, c, 0, 0, 0);
}

// XOR-swizzled LDS byte offset: 16B-granule index XORed with (row&7).
__device__ __forceinline__ int swz(int row, int colByte, int strideB) {
  return row * strideB + ((((colByte >> 4) ^ (row & 7)) << 4) | (colByte & 15));
}

// lgkm-only barrier: orders LDS producer->consumer, leaves global loads in
// flight. Proven r5-r11.
__device__ __forceinline__ void barrier_nd() {
  asm volatile("s_waitcnt lgkmcnt(0)" ::: "memory");
  __builtin_amdgcn_s_barrier();
  asm volatile("" ::: "memory");
}

union CvtU { bf16x2 h; unsigned int u; };
union PaU { unsigned int u[4]; bf16x8 v; };

// ws: bf16 weights only. q_wb [0,36864) PRE-SCALED by SCALE, kv_wb
// [36864,110592), proj_wb [110592,147456). 294912 bytes.
__global__ void prep(const float* __restrict__ qw, const float* __restrict__ kvw,
                     const float* __restrict__ pw, bf16_t* __restrict__ wsb) {
  int i = blockIdx.x * 256 + threadIdx.x;
#pragma unroll
  for (int j = 0; j < 4; ++j) {
    int e = i * 4 + j;
    float v;
    if (e < 36864) v = qw[e] * SCALE;
    else if (e < 110592) v = kvw[e - 36864];
    else v = pw[e - 110592];
    wsb[e] = (bf16_t)v;
  }
}

template <bool WS>
__device__ __forceinline__ bf16x8 ldw(const bf16_t* __restrict__ wb,
                                      const float* __restrict__ wf, int off) {
  if constexpr (WS) {
    return *(const bf16x8*)(wb + off);
  } else {
    const float4* p = (const float4*)(wf + off);
    float4 a = p[0], c = p[1];
    bf16x8 r;
    r[0] = (bf16_t)a.x; r[1] = (bf16_t)a.y; r[2] = (bf16_t)a.z; r[3] = (bf16_t)a.w;
    r[4] = (bf16_t)c.x; r[5] = (bf16_t)c.y; r[6] = (bf16_t)c.z; r[7] = (bf16_t)c.w;
    return r;
  }
}

// One block = TWO windows (win0=2b, win1=2b+1). 512 threads = 8 waves.
// LDS = 144 KB -> 1 block/CU:
//   RA @      0 : [128][384B] x2 staged -> Q -> att-out (rows wv*64+n)
//   RK @  49152 : [128][384B] K (both windows)
//   RV @  98304 : [2][192][128B] V^T per window
// r12 = r7 + ONE change: x1 kh0-half (12 float4 = 48 VGPR/wave) prefetched at
// stage time so the x1 HBM stream overlaps x2 burst + phase A (r10-proven
// safe single 48-reg barrier crossing). Everything else identical to r7.
template <bool WS>
__global__ __launch_bounds__(512, 2) void wca_main(
    const float* __restrict__ x1, const float* __restrict__ x2,
    const float* __restrict__ mask,
    const float* __restrict__ qw_f, const float* __restrict__ qb,
    const float* __restrict__ kvw_f, const float* __restrict__ kvb,
    const float* __restrict__ pw_f, const float* __restrict__ pb,
    const float* __restrict__ table,
    const bf16_t* __restrict__ wsb,
    float* __restrict__ out) {
  extern __shared__ char smem[];
  char* RA = smem;
  char* RK = smem + 49152;
  char* RV = smem + 98304;

  const int t = threadIdx.x;
  const int w = t >> 6, l = t & 63, lo = l & 15, hi = l >> 4;
  const int win0 = 2 * blockIdx.x;

  const bf16_t* q_wb = wsb;
  const bf16_t* kv_wb = wsb + 36864;
  const bf16_t* p_wb = wsb + 110592;

  // phase-B wave mapping (also used for the prefetch addressing)
  const int wvB = w >> 2, rt2B = (w >> 1) & 1, cgB = w & 1;
  const float* x1w = x1 + (size_t)(win0 + wvB) * 12288;

  // ---------- stage x2 (both windows) -> RA  [+ x1 kh0 prefetch] ----------
  float4 xp[12];  // x1 kh0 half; crosses stage->A and A->B barriers
  {
    const float4* s2a = (const float4*)(x2 + (size_t)win0 * 12288);
    const float4* s2b = (const float4*)(x2 + (size_t)(win0 + 1) * 12288);
    float4 ld[12];
#pragma unroll
    for (int it = 0; it < 3; ++it) {
      int idx = it * 512 + t;
      ld[4 * it + 0] = s2a[2 * idx]; ld[4 * it + 1] = s2a[2 * idx + 1];
      ld[4 * it + 2] = s2b[2 * idx]; ld[4 * it + 3] = s2b[2 * idx + 1];
    }
    // x1 kh0 prefetch: rows rt2B*32 + rt*16 + lo, k-chunks 0..2
#pragma unroll
    for (int rt = 0; rt < 2; ++rt) {
      const float4* p = (const float4*)(x1w + (rt2B * 32 + rt * 16 + lo) * 192);
#pragma unroll
      for (int k2 = 0; k2 < 3; ++k2) {
        xp[rt * 6 + k2 * 2 + 0] = p[k2 * 8 + hi * 2];
        xp[rt * 6 + k2 * 2 + 1] = p[k2 * 8 + hi * 2 + 1];
      }
    }
#pragma unroll
    for (int it = 0; it < 3; ++it) {
      int idx = it * 512 + t;
      int n = idx / 24, g = idx - n * 24;
      bf16x8 v;
      float4 a = ld[4 * it + 0], c = ld[4 * it + 1];
      v[0] = (bf16_t)a.x; v[1] = (bf16_t)a.y; v[2] = (bf16_t)a.z; v[3] = (bf16_t)a.w;
      v[4] = (bf16_t)c.x; v[5] = (bf16_t)c.y; v[6] = (bf16_t)c.z; v[7] = (bf16_t)c.w;
      *(bf16x8*)(RA + swz(n, g * 16, 384)) = v;
      a = ld[4 * it + 2]; c = ld[4 * it + 3];
      v[0] = (bf16_t)a.x; v[1] = (bf16_t)a.y; v[2] = (bf16_t)a.z; v[3] = (bf16_t)a.w;
      v[4] = (bf16_t)c.x; v[5] = (bf16_t)c.y; v[6] = (bf16_t)c.z; v[7] = (bf16_t)c.w;
      *(bf16x8*)(RA + swz(64 + n, g * 16, 384)) = v;
    }
  }
  barrier_nd();

  // ---------- phase A: KV proj, weights preloaded once, 2 windows ----------
  // wave w: K cols w*48.. (w<4) | V cols (w-4)*48.. (w>=4). Full dedup.
  {
    bf16x8 wA[6][3];
#pragma unroll
    for (int kk = 0; kk < 6; ++kk)
#pragma unroll
      for (int ct = 0; ct < 3; ++ct) {
        int row = w * 48 + ct * 16 + lo;
        wA[kk][ct] = ldw<WS>(kv_wb, kvw_f, row * 192 + kk * 32 + hi * 8);
      }
    for (int wv = 0; wv < 2; ++wv) {
      f32x4 acc[4][3];
#pragma unroll
      for (int rt = 0; rt < 4; ++rt)
#pragma unroll
        for (int ct = 0; ct < 3; ++ct) { f32x4 z = {0.f, 0.f, 0.f, 0.f}; acc[rt][ct] = z; }
#pragma unroll
      for (int kk = 0; kk < 6; ++kk) {
        bf16x8 a[4];
#pragma unroll
        for (int rt = 0; rt < 4; ++rt)
          a[rt] = *(const bf16x8*)(RA + swz(wv * 64 + rt * 16 + lo, (kk * 4 + hi) * 16, 384));
#pragma unroll
        for (int rt = 0; rt < 4; ++rt)
#pragma unroll
          for (int ct = 0; ct < 3; ++ct)
            acc[rt][ct] = mfma16(a[rt], wA[kk][ct], acc[rt][ct]);
      }
      if (w < 4) {
#pragma unroll
        for (int ct = 0; ct < 3; ++ct) {
          int och = w * 48 + ct * 16 + lo;
          float bv = kvb[och];
#pragma unroll
          for (int rt = 0; rt < 4; ++rt)
#pragma unroll
            for (int i = 0; i < 4; ++i)
              *(bf16_t*)(RK + swz(wv * 64 + rt * 16 + hi * 4 + i, och * 2, 384)) =
                  (bf16_t)(acc[rt][ct][i] + bv);
        }
      } else {
#pragma unroll
        for (int ct = 0; ct < 3; ++ct) {
          int och = (w - 4) * 48 + ct * 16 + lo;
          float bv = kvb[192 + och];
#pragma unroll
          for (int rt = 0; rt < 4; ++rt) {
            int n0 = rt * 16 + hi * 4;
            bf16x4 pk;
#pragma unroll
            for (int i = 0; i < 4; ++i) pk[i] = (bf16_t)(acc[rt][ct][i] + bv);
            *(bf16x4*)(RV + wv * 24576 + swz(och, n0 * 2, 128)) = pk;
          }
        }
      }
    }
  }
  barrier_nd();  // x2 reads done; K, V^T ready

  // ---------- phase B: Q proj (kh0 from xp prefetch, kh1 fresh) -> RA ----------
  // wave: wvB, rt2B (32 rows), cgB (96 cols)
  {
    f32x4 acc[2][6];
#pragma unroll
    for (int rt = 0; rt < 2; ++rt)
#pragma unroll
      for (int ct = 0; ct < 6; ++ct) { f32x4 z = {0.f, 0.f, 0.f, 0.f}; acc[rt][ct] = z; }
#pragma unroll
    for (int kh = 0; kh < 2; ++kh) {
      float4 xf[2][3][2];
      if (kh == 0) {
#pragma unroll
        for (int rt = 0; rt < 2; ++rt)
#pragma unroll
          for (int k2 = 0; k2 < 3; ++k2) {
            xf[rt][k2][0] = xp[rt * 6 + k2 * 2 + 0];
            xf[rt][k2][1] = xp[rt * 6 + k2 * 2 + 1];
          }
      } else {
#pragma unroll
        for (int rt = 0; rt < 2; ++rt) {
          const float4* p = (const float4*)(x1w + (rt2B * 32 + rt * 16 + lo) * 192);
#pragma unroll
          for (int k2 = 0; k2 < 3; ++k2) {
            xf[rt][k2][0] = p[(kh * 3 + k2) * 8 + hi * 2];
            xf[rt][k2][1] = p[(kh * 3 + k2) * 8 + hi * 2 + 1];
          }
        }
      }
      bf16x8 wB[3][6];
#pragma unroll
      for (int k2 = 0; k2 < 3; ++k2)
#pragma unroll
        for (int ct = 0; ct < 6; ++ct) {
          int col = cgB * 96 + ct * 16 + lo;
          wB[k2][ct] = ldw<WS>(q_wb, qw_f, col * 192 + (kh * 3 + k2) * 32 + hi * 8);
        }
#pragma unroll
      for (int k2 = 0; k2 < 3; ++k2)
#pragma unroll
        for (int rt = 0; rt < 2; ++rt) {
          bf16x8 a;
          float4 xa = xf[rt][k2][0], xb = xf[rt][k2][1];
          a[0] = (bf16_t)xa.x; a[1] = (bf16_t)xa.y; a[2] = (bf16_t)xa.z; a[3] = (bf16_t)xa.w;
          a[4] = (bf16_t)xb.x; a[5] = (bf16_t)xb.y; a[6] = (bf16_t)xb.z; a[7] = (bf16_t)xb.w;
#pragma unroll
          for (int ct = 0; ct < 6; ++ct) acc[rt][ct] = mfma16(a, wB[k2][ct], acc[rt][ct]);
        }
    }
#pragma unroll
    for (int ct = 0; ct < 6; ++ct) {
      int col = cgB * 96 + ct * 16 + lo;
      float qbs = qb[col] * SCALE;
#pragma unroll
      for (int rt = 0; rt < 2; ++rt)
#pragma unroll
        for (int i = 0; i < 4; ++i) {
          int row = wvB * 64 + rt2B * 32 + rt * 16 + hi * 4 + i;
          float val = WS ? (acc[rt][ct][i] + qbs) : (acc[rt][ct][i] + qb[col]) * SCALE;
          *(bf16_t*)(RA + swz(row, col * 2, 384)) = (bf16_t)val;
        }
    }
  }
  barrier_nd();  // Q ready

  // ---------- attention: wave = (wv = w>>2, rt32 = (w>>1)&1, hh = w&1) ----------
  // Per wave: 32 q-rows (2 sub-tiles of 16) x 3 heads. Bias via 5.4 KB table
  // gather (L1-resident). att-out overwrites Q in RA, no barriers.
  {
    const int wv = w >> 2, rt32 = (w >> 1) & 1, hh = w & 1;
    const int win = win0 + wv;
    const float* maskb = mask + (size_t)(win & 1023) * 4096;
    f32x4 mk[2][4];
    int ridx[2][4][4];
#pragma unroll
    for (int rts = 0; rts < 2; ++rts) {
      int r = rt32 * 32 + rts * 16 + lo;
#pragma unroll
      for (int ct = 0; ct < 4; ++ct) {
        mk[rts][ct] = *(const f32x4*)(maskb + r * 64 + ct * 16 + hi * 4);
#pragma unroll
        for (int i = 0; i < 4; ++i) {
          int c = ct * 16 + hi * 4 + i;
          ridx[rts][ct][i] = (((r >> 3) - (c >> 3) + 7) * 15 + ((r & 7) - (c & 7) + 7)) * 6;
        }
      }
    }
#pragma unroll
    for (int hq = 0; hq < 3; ++hq) {
      const int h = hh * 3 + hq;
#pragma unroll
      for (int rts = 0; rts < 2; ++rts) {
        const int rbase = rt32 * 32 + rts * 16;
        const int r = rbase + lo;
        bf16x8 qa = *(const bf16x8*)(RA + swz(wv * 64 + r, h * 64 + hi * 16, 384));
        f32x4 s[4];
#pragma unroll
        for (int ct = 0; ct < 4; ++ct) {
          f32x4 ci;
#pragma unroll
          for (int i = 0; i < 4; ++i) ci[i] = table[ridx[rts][ct][i] + h];
          ci += mk[rts][ct];
          bf16x8 ka = *(const bf16x8*)(RK + swz(wv * 64 + ct * 16 + lo, h * 64 + hi * 16, 384));
          s[ct] = mfma16(ka, qa, ci);  // S^T: lane holds S[r][ct*16+hi*4+i]
        }
        float mx = -1e30f;
#pragma unroll
        for (int ct = 0; ct < 4; ++ct)
#pragma unroll
          for (int i = 0; i < 4; ++i) mx = fmaxf(mx, s[ct][i]);
        mx = fmaxf(mx, __shfl_xor(mx, 16));
        mx = fmaxf(mx, __shfl_xor(mx, 32));
        float sum = 0.f;
#pragma unroll
        for (int ct = 0; ct < 4; ++ct)
#pragma unroll
          for (int i = 0; i < 4; ++i) {
            float p = __expf(s[ct][i] - mx);
            s[ct][i] = p;
            sum += p;
          }
        sum += __shfl_xor(sum, 16);
        sum += __shfl_xor(sum, 32);
        float rinv = 1.0f / sum;
        unsigned int word[4][2];
#pragma unroll
        for (int ct = 0; ct < 4; ++ct)
#pragma unroll
          for (int i2 = 0; i2 < 2; ++i2) {
            CvtU cu;
            cu.h[0] = (bf16_t)(s[ct][2 * i2] * rinv);
            cu.h[1] = (bf16_t)(s[ct][2 * i2 + 1] * rinv);
            word[ct][i2] = cu.u;
          }
        // PV: build A-frag P[rbase+lo][k-run] via shfl word-pulls
        f32x4 o0 = {0.f, 0.f, 0.f, 0.f}, o1 = {0.f, 0.f, 0.f, 0.f};
#pragma unroll
        for (int k2 = 0; k2 < 2; ++k2) {
          PaU pa;
#pragma unroll
          for (int j2 = 0; j2 < 4; ++j2) {
            int src = lo + ((hi & 1) << 5) + ((j2 >> 1) << 4);
            unsigned int wa = (unsigned int)__shfl((int)word[2 * k2][j2 & 1], src);
            unsigned int wb = (unsigned int)__shfl((int)word[2 * k2 + 1][j2 & 1], src);
            pa.u[j2] = (hi & 2) ? wb : wa;
          }
          bf16x8 v0 = *(const bf16x8*)(RV + wv * 24576 + swz(h * 32 + lo, k2 * 64 + hi * 16, 128));
          bf16x8 v1 = *(const bf16x8*)(RV + wv * 24576 + swz(h * 32 + 16 + lo, k2 * 64 + hi * 16, 128));
          o0 = mfma16(pa.v, v0, o0);
          o1 = mfma16(pa.v, v1, o1);
        }
#pragma unroll
        for (int i = 0; i < 4; ++i) {
          int rr = wv * 64 + rbase + hi * 4 + i;
          *(bf16_t*)(RA + swz(rr, h * 64 + lo * 2, 384)) = (bf16_t)o0[i];
          *(bf16_t*)(RA + swz(rr, h * 64 + 32 + lo * 2, 384)) = (bf16_t)o1[i];
        }
      }
    }
  }
  barrier_nd();  // att-out fully in RA

  // ---------- out proj: wave = (wv = w>>2, cgo = w&3 -> 48 cols) ----------
  {
    const int wv = w >> 2, cgo = w & 3;
    bf16x8 wO[6][3];
#pragma unroll
    for (int kk = 0; kk < 6; ++kk)
#pragma unroll
      for (int ct = 0; ct < 3; ++ct) {
        int col = cgo * 48 + ct * 16 + lo;
        wO[kk][ct] = ldw<WS>(p_wb, pw_f, col * 192 + kk * 32 + hi * 8);
      }
    f32x4 acc[4][3];
#pragma unroll
    for (int rt = 0; rt < 4; ++rt)
#pragma unroll
      for (int ct = 0; ct < 3; ++ct) { f32x4 z = {0.f, 0.f, 0.f, 0.f}; acc[rt][ct] = z; }
#pragma unroll
    for (int kk = 0; kk < 6; ++kk) {
      bf16x8 a[4];
#pragma unroll
      for (int rt = 0; rt < 4; ++rt)
        a[rt] = *(const bf16x8*)(RA + swz(wv * 64 + rt * 16 + lo, (kk * 4 + hi) * 16, 384));
#pragma unroll
      for (int rt = 0; rt < 4; ++rt)
#pragma unroll
        for (int ct = 0; ct < 3; ++ct)
          acc[rt][ct] = mfma16(a[rt], wO[kk][ct], acc[rt][ct]);
    }
    float* outp = out + (size_t)(win0 + wv) * 12288;
#pragma unroll
    for (int ct = 0; ct < 3; ++ct) {
      int col = cgo * 48 + ct * 16 + lo;
      float bv = pb[col];
#pragma unroll
      for (int rt = 0; rt < 4; ++rt)
#pragma unroll
        for (int i = 0; i < 4; ++i)
          outp[(rt * 16 + hi * 4 + i) * 192 + col] = acc[rt][ct][i] + bv;
    }
  }
}

extern "C" void kernel_launch(void* const* d_in, const int* in_sizes, int n_in,
                              void* d_out, int out_size, void* d_ws, size_t ws_size,
                              hipStream_t stream) {
  const float* x1 = (const float*)d_in[0];
  const float* x2 = (const float*)d_in[1];
  const float* mask = (const float*)d_in[2];
  const float* qw = (const float*)d_in[3];
  const float* qb = (const float*)d_in[4];
  const float* kvw = (const float*)d_in[5];
  const float* kvb = (const float*)d_in[6];
  const float* pw = (const float*)d_in[7];
  const float* pb = (const float*)d_in[8];
  const float* table = (const float*)d_in[9];
  float* out = (float*)d_out;
  bf16_t* wsb = (bf16_t*)d_ws;
  const int LDS_BYTES = 147456;
  if (ws_size >= 294912) {
    prep<<<144, 256, 0, stream>>>(qw, kvw, pw, wsb);
    wca_main<true><<<4096, 512, LDS_BYTES, stream>>>(x1, x2, mask, qw, qb, kvw, kvb,
                                                     pw, pb, table, wsb, out);
  } else {
    wca_main<false><<<4096, 512, LDS_BYTES, stream>>>(x1, x2, mask, qw, qb, kvw, kvb,
                                                      pw, pb, table, wsb, out);
  }
}